// Round 3
// baseline (2374.354 us; speedup 1.0000x reference)
//
#include <hip/hip_runtime.h>

typedef unsigned short u16;
typedef unsigned int u32;

using f32x4 = __attribute__((ext_vector_type(4))) float;
using bf16x8 = __attribute__((ext_vector_type(8))) __bf16;

// ---------- constants ----------
#define HN 2048
#define KVD 512
#define TOKENS 2048          // B*T
#define N1 3712              // GEMM1 N (3648 padded to 29*128)
#define K2W 576              // GEMM2 K
#define N2 7168              // GEMM2 N: w(2048) a(2048) g(2048) v(512) k(512)

// ---------- workspace layout (bytes) — lifetime-aliased, peak 213.4 MB ----------
// Region A [0, 30408704): Y1 (GEMM1 out; dead after k_prep_rec) -> OO + XG
#define OFF_Y1   0ull
#define OFF_OO   0ull                         // after Y1 dead (16,777,216)
#define OFF_XG   16777216ull                  // after Y1 dead (8,388,608)
// Region B [30408704, 89128960): Y2 (dead after k_gate) -> OUTR
#define OFF_Y2   30408704ull
#define OFF_OUTR 30408704ull                  // after Y2 dead (16,777,216)
// Region C [89128960, 112721920): BT1+XB -> W2T+X2 -> OT
#define OFF_BT1  89128960ull                  // (15,204,352) until GEMM1
#define OFF_XB   104333312ull                 // (8,388,608)  until GEMM1
#define OFF_W2T  89128960ull                  // (8,257,536)  after GEMM1, until GEMM2
#define OFF_X2   97386496ull                  // (2,359,296)  after GEMM1, until GEMM2
#define OFF_OT   89128960ull                  // (8,388,608)  after GEMM2, until GEMM3
// Region D [112721920, 213385216): recurrence operands (f32)
#define OFF_RR   112721920ull
#define OFF_DEC  129499136ull
#define OFF_KR   146276352ull
#define OFF_VV   163053568ull
#define OFF_AA   179830784ull
#define OFF_BB   196608000ull
#define WS_NEED  213385216ull

// ---------- helpers ----------
__device__ __forceinline__ u16 f2bf(float f) {
    u32 u = __float_as_uint(f);
    u32 r = u + 0x7fffu + ((u >> 16) & 1u);
    return (u16)(r >> 16);
}
__device__ __forceinline__ float sigm(float x) { return 1.f / (1.f + expf(-x)); }
__device__ __forceinline__ float wsum(float v) {
#pragma unroll
    for (int m = 32; m > 0; m >>= 1) v += __shfl_xor(v, m, 64);
    return v;
}

typedef __attribute__((address_space(1))) const void glob_t;
typedef __attribute__((address_space(3))) void lds_t;
__device__ __forceinline__ void gload_lds16(const void* g, void* l) {
    __builtin_amdgcn_global_load_lds((glob_t*)g, (lds_t*)l, 16, 0, 0);
}

// ---------- weight prep ----------
__global__ __launch_bounds__(256) void k_prep_bt1(const float* __restrict__ wavgk1,
                                                  const float* __restrict__ RKV,
                                                  u16* __restrict__ BT1) {
    int idx = blockIdx.x * 256 + threadIdx.x;   // n*2048 + k, n<3712
    int n = idx >> 11, k = idx & 2047;
    float v = 0.f;
    if (n < 576) v = wavgk1[(size_t)k * 576 + n];
    else if (n < 3648) v = RKV[(size_t)k * 3072 + (n - 576)];
    BT1[idx] = f2bf(v);
}

__global__ __launch_bounds__(256) void k_prep_w2t(const float* __restrict__ w2, const float* __restrict__ a2,
                                                  const float* __restrict__ g2, const float* __restrict__ v2,
                                                  const float* __restrict__ k2, u16* __restrict__ W2T) {
    int idx = blockIdx.x * 256 + threadIdx.x;   // n*576 + c, n<7168
    int n = idx / 576, c = idx - n * 576;
    float v = 0.f;
    if (n < 2048)      { if (c < 96)              v = w2[(size_t)c * 2048 + n]; }
    else if (n < 4096) { if (c >= 96 && c < 192)  v = a2[(size_t)(c - 96) * 2048 + (n - 2048)]; }
    else if (n < 6144) { if (c >= 192 && c < 448) v = g2[(size_t)(c - 192) * 2048 + (n - 4096)]; }
    else if (n < 6656) { if (c >= 448 && c < 512) v = v2[(size_t)(c - 448) * 512 + (n - 6144)]; }
    else               { if (c >= 512)            v = k2[(size_t)(c - 512) * 512 + (n - 6656)]; }
    W2T[idx] = f2bf(v);
}

__global__ __launch_bounds__(256) void k_prep_ot(const float* __restrict__ O, u16* __restrict__ OT) {
    int idx = blockIdx.x * 256 + threadIdx.x;   // n*2048 + k
    int n = idx >> 11, k = idx & 2047;
    OT[idx] = f2bf(O[(size_t)k * 2048 + n]);
}

// ---------- rmsnorm(x_in, ln1) -> bf16 ----------
__global__ __launch_bounds__(256) void k_rms1(const float* __restrict__ X,
                                              const float* __restrict__ ln1,
                                              u16* __restrict__ XB) {
    const int t = blockIdx.x, tid = threadIdx.x;
    const float* row = X + ((size_t)t << 11);
    float4 v0 = *(const float4*)(row + tid * 8);
    float4 v1 = *(const float4*)(row + tid * 8 + 4);
    float ss = v0.x*v0.x + v0.y*v0.y + v0.z*v0.z + v0.w*v0.w
             + v1.x*v1.x + v1.y*v1.y + v1.z*v1.z + v1.w*v1.w;
    ss = wsum(ss);
    __shared__ float red[4];
    if ((tid & 63) == 0) red[tid >> 6] = ss;
    __syncthreads();
    float scale = rsqrtf((red[0] + red[1] + red[2] + red[3]) * (1.f / 2048.f) + 1e-6f);
    float4 w0_ = *(const float4*)(ln1 + tid * 8);
    float4 w1_ = *(const float4*)(ln1 + tid * 8 + 4);
    u16* o = XB + ((size_t)t << 11) + tid * 8;
    o[0] = f2bf(v0.x * scale * w0_.x); o[1] = f2bf(v0.y * scale * w0_.y);
    o[2] = f2bf(v0.z * scale * w0_.z); o[3] = f2bf(v0.w * scale * w0_.w);
    o[4] = f2bf(v1.x * scale * w1_.x); o[5] = f2bf(v1.y * scale * w1_.y);
    o[6] = f2bf(v1.z * scale * w1_.z); o[7] = f2bf(v1.w * scale * w1_.w);
}

// ---------- generic bf16 MFMA GEMM: C(MxN f32) = A(MxK bf16) * Bt(NxK bf16)^T ----------
__global__ __launch_bounds__(256) void k_gemm(const u16* __restrict__ A,
                                              const u16* __restrict__ Bt,
                                              float* __restrict__ C,
                                              int M, int N, int K) {
    __shared__ __align__(16) u16 tA[4096];  // [128 rows][32 k]
    __shared__ __align__(16) u16 tB[4096];
    const int tid = threadIdx.x;
    const int w = tid >> 6, l = tid & 63;
    const int bm = blockIdx.x << 7, bn = blockIdx.y << 7;
    const int wm = (w >> 1) << 6, wn = (w & 1) << 6;
    const int lrow = l >> 2;        // 0..15
    const int lk = (l & 3) << 3;    // 0,8,16,24
    f32x4 acc[4][4] = {};
    const size_t rA0 = (size_t)(bm + (w << 4) + lrow) * K;
    const size_t rA1 = (size_t)(bm + ((w + 4) << 4) + lrow) * K;
    const size_t rB0 = (size_t)(bn + (w << 4) + lrow) * K;
    const size_t rB1 = (size_t)(bn + ((w + 4) << 4) + lrow) * K;
    const int frow = l & 15, koff = (l >> 4) << 3;
    for (int kt = 0; kt < K; kt += 32) {
        gload_lds16(A + rA0 + kt + lk, &tA[w << 9]);
        gload_lds16(A + rA1 + kt + lk, &tA[2048 + (w << 9)]);
        gload_lds16(Bt + rB0 + kt + lk, &tB[w << 9]);
        gload_lds16(Bt + rB1 + kt + lk, &tB[2048 + (w << 9)]);
        __syncthreads();
        bf16x8 av[4], bv[4];
#pragma unroll
        for (int i = 0; i < 4; ++i) {
            av[i] = *(const bf16x8*)&tA[((wm + (i << 4) + frow) << 5) + koff];
            bv[i] = *(const bf16x8*)&tB[((wn + (i << 4) + frow) << 5) + koff];
        }
#pragma unroll
        for (int i = 0; i < 4; ++i)
#pragma unroll
            for (int j = 0; j < 4; ++j)
                acc[i][j] = __builtin_amdgcn_mfma_f32_16x16x32_bf16(av[i], bv[j], acc[i][j], 0, 0, 0);
        __syncthreads();
    }
    const int crow = bm + wm + ((l >> 4) << 2);
    const int ccol = bn + wn + (l & 15);
#pragma unroll
    for (int i = 0; i < 4; ++i)
#pragma unroll
        for (int j = 0; j < 4; ++j)
#pragma unroll
            for (int jj = 0; jj < 4; ++jj)
                C[(size_t)(crow + (i << 4) + jj) * N + ccol + (j << 4)] = acc[i][j][jj];
}

// ---------- Y1 -> X2 (bf16): [tanh(xw) | xa | sigmoid(xg) | xv | xk] ----------
__global__ __launch_bounds__(256) void k_prep_x2(const float* __restrict__ Y1, u16* __restrict__ X2) {
    int idx = blockIdx.x * 256 + threadIdx.x;   // t*576 + c
    int t = idx / 576, c = idx - t * 576;
    const float* y1 = Y1 + (size_t)t * N1;
    float v;
    if (c < 96)       v = tanhf(y1[c]);
    else if (c < 192) v = y1[c];
    else if (c < 448) v = sigm(y1[c + 64]);
    else if (c < 512) v = y1[c - 256];
    else              v = y1[c];
    X2[idx] = f2bf(v);
}

// ---------- per-token recurrence prep ----------
__global__ __launch_bounds__(256) void k_prep_rec(
    const float* __restrict__ Y1, const float* __restrict__ Y2,
    const float* __restrict__ v_first, const float* __restrict__ k_first,
    const float* __restrict__ cosb, const float* __restrict__ sinb,
    const float* __restrict__ w0, const float* __restrict__ a0,
    const float* __restrict__ v0b, const float* __restrict__ k0b,
    const float* __restrict__ R_bias, const float* __restrict__ K_bias,
    const float* __restrict__ V_bias, const float* __restrict__ ln_r,
    const float* __restrict__ ln_k,
    float* __restrict__ RR, float* __restrict__ DEC, float* __restrict__ KR,
    float* __restrict__ VV, float* __restrict__ AA, float* __restrict__ BB) {
    const int t = blockIdx.x, tid = threadIdx.x;
    const int ww = tid >> 6, lane = tid & 63;
    const float* y1 = Y1 + (size_t)t * N1;
    const float* y2 = Y2 + (size_t)t * N2;
    const float cs = cosb[t * 64 + lane];
    const float sn = sinb[t * 64 + lane];
    const float sign = lane < 32 ? -1.f : 1.f;
    const size_t tb = (size_t)t << 11;
    __shared__ float kkv[512], vkv[512];
    // r: per-head rmsnorm + rope
#pragma unroll
    for (int i = 0; i < 8; ++i) {
        int h = ww * 8 + i, c = h * 64 + lane;
        float rr = y1[576 + c] + R_bias[c];
        float ssq = wsum(rr * rr);
        float rn = ln_r[lane] * rr * rsqrtf(ssq * (1.f / 64.f) + 1e-6f);
        float rot = sign * __shfl(rn, lane ^ 32, 64);
        RR[tb + c] = rn * cs + rot * sn;
    }
    // k,v kv-heads: rmsnorm+rope+mix
#pragma unroll
    for (int i = 0; i < 2; ++i) {
        int j = ww * 2 + i, c = j * 64 + lane;
        float kr = y1[2624 + c] + K_bias[c];
        float ssq = wsum(kr * kr);
        float kn = ln_k[lane] * kr * rsqrtf(ssq * (1.f / 64.f) + 1e-6f);
        float rot = sign * __shfl(kn, lane ^ 32, 64);
        float krope = kn * cs + rot * sn;
        float ksig = sigm(y2[6656 + c] + k0b[c]);
        kkv[c] = krope + (k_first[(size_t)t * 512 + c] - krope) * ksig;
        float vr = y1[3136 + c] + V_bias[c];
        float vsig = sigm(y2[6144 + c] + v0b[c]);
        vkv[c] = vr + (v_first[(size_t)t * 512 + c] - vr) * vsig;
    }
    __syncthreads();
    // per-head final recurrence operands
#pragma unroll
    for (int i = 0; i < 8; ++i) {
        int h = ww * 8 + i, c = h * 64 + lane;
        int ckv = (h >> 2) * 64 + lane;
        float kb = kkv[ckv], vb = vkv[ckv];
        float a_ = sigm(y2[2048 + c] + a0[c]);
        float wr = y2[c] + w0[c];
        float z = -wr;
        float sp = fmaxf(z, 0.f) + log1pf(expf(-fabsf(z)));
        float w_log = -sp - 0.5f;
        float ssq = wsum(kb * kb);
        float kk = kb / fmaxf(sqrtf(ssq), 1e-12f);
        DEC[tb + c] = expf(-expf(w_log));
        KR[tb + c] = kb * (1.f - w_log + a_);
        VV[tb + c] = vb;
        AA[tb + c] = -kk;
        BB[tb + c] = kk * a_;
    }
}

// ---------- sequential recurrence: 1 wave per (b,h), lane = v-column ----------
__global__ __launch_bounds__(64) void k_rec(
    const float* __restrict__ RRp, const float* __restrict__ DECp,
    const float* __restrict__ KRp, const float* __restrict__ VVp,
    const float* __restrict__ AAp, const float* __restrict__ BBp,
    const float* __restrict__ S0, float* __restrict__ OO) {
    const int bh = blockIdx.x, lane = threadIdx.x;
    float S[64];
    const float* s0 = S0 + ((size_t)bh << 12);
#pragma unroll
    for (int k = 0; k < 64; ++k) S[k] = s0[(k << 6) + lane];
    __shared__ float lA[64];
    __shared__ float4 lQ[64];
    const size_t base = ((size_t)(bh >> 5) * 1024 * 2048) + ((size_t)(bh & 31) << 6) + lane;
    size_t ix = base;
    float aa = AAp[ix];
    float4 q = make_float4(DECp[ix], KRp[ix], BBp[ix], RRp[ix]);
    float vt = VVp[ix];
    for (int t = 0; t < 1024; ++t) {
        lA[lane] = aa;          // wave-synchronous LDS: in-order DS pipe, no barrier
        lQ[lane] = q;
        const size_t nx = base + ((size_t)(t < 1023 ? t + 1 : t) << 11);
        float aan = AAp[nx];
        float4 qn = make_float4(DECp[nx], KRp[nx], BBp[nx], RRp[nx]);
        float vtn = VVp[nx];
        float s0a = 0.f, s1a = 0.f, s2a = 0.f, s3a = 0.f;
#pragma unroll
        for (int k = 0; k < 64; k += 4) {
            s0a = fmaf(lA[k], S[k], s0a);
            s1a = fmaf(lA[k + 1], S[k + 1], s1a);
            s2a = fmaf(lA[k + 2], S[k + 2], s2a);
            s3a = fmaf(lA[k + 3], S[k + 3], s3a);
        }
        const float sa = (s0a + s1a) + (s2a + s3a);
        const float vtc = vt;
        float o0 = 0.f, o1 = 0.f, o2 = 0.f, o3 = 0.f;
#pragma unroll
        for (int k = 0; k < 64; k += 4) {
#pragma unroll
            for (int u = 0; u < 4; ++u) {
                float4 p = lQ[k + u];
                float s = S[k + u] * p.x;
                s = fmaf(p.y, vtc, s);
                s = fmaf(p.z, sa, s);
                S[k + u] = s;
                if (u == 0) o0 = fmaf(p.w, s, o0);
                else if (u == 1) o1 = fmaf(p.w, s, o1);
                else if (u == 2) o2 = fmaf(p.w, s, o2);
                else o3 = fmaf(p.w, s, o3);
            }
        }
        OO[base + ((size_t)t << 11)] = (o0 + o1) + (o2 + o3);
        aa = aan; q = qn; vt = vtn;
    }
}

// ---------- bonus + gate -> bf16 ----------
__global__ __launch_bounds__(256) void k_gate(
    const float* __restrict__ OOp, const float* __restrict__ RRp,
    const float* __restrict__ KRp, const float* __restrict__ VVp,
    const float* __restrict__ Y2, const float* __restrict__ r_k,
    u16* __restrict__ XG) {
    const int t = blockIdx.x, tid = threadIdx.x;
    const int ww = tid >> 6, lane = tid & 63;
    const size_t tb = (size_t)t << 11;
#pragma unroll
    for (int i = 0; i < 8; ++i) {
        int c = (ww * 8 + i) * 64 + lane;
        float pr = RRp[tb + c] * KRp[tb + c] * r_k[c];
        float dot = wsum(pr);
        float xx = OOp[tb + c] * 0.125f + dot * VVp[tb + c];
        float g = Y2[(size_t)t * N2 + 4096 + c];
        XG[tb + c] = f2bf(xx * g);
    }
}

// ---------- final residual + rmsnorm ----------
__global__ __launch_bounds__(256) void k_final(const float* __restrict__ x_in,
                                               const float* __restrict__ OUTR,
                                               const float* __restrict__ ln2,
                                               float* __restrict__ out) {
    const int t = blockIdx.x, tid = threadIdx.x;
    const float* xr = x_in + ((size_t)t << 11);
    const float* orow = OUTR + ((size_t)t << 11);
    float4 a0 = *(const float4*)(xr + tid * 8);
    float4 a1 = *(const float4*)(xr + tid * 8 + 4);
    float4 b0 = *(const float4*)(orow + tid * 8);
    float4 b1 = *(const float4*)(orow + tid * 8 + 4);
    float v[8] = {a0.x + b0.x, a0.y + b0.y, a0.z + b0.z, a0.w + b0.w,
                  a1.x + b1.x, a1.y + b1.y, a1.z + b1.z, a1.w + b1.w};
    float ss = 0.f;
#pragma unroll
    for (int i = 0; i < 8; ++i) ss = fmaf(v[i], v[i], ss);
    ss = wsum(ss);
    __shared__ float red[4];
    if ((tid & 63) == 0) red[tid >> 6] = ss;
    __syncthreads();
    float scale = rsqrtf((red[0] + red[1] + red[2] + red[3]) * (1.f / 2048.f) + 1e-6f);
    float* o = out + ((size_t)t << 11) + tid * 8;
#pragma unroll
    for (int i = 0; i < 8; ++i) o[i] = ln2[tid * 8 + i] * v[i] * scale;
}

extern "C" void kernel_launch(void* const* d_in, const int* in_sizes, int n_in,
                              void* d_out, int out_size, void* d_ws, size_t ws_size,
                              hipStream_t stream) {
    const float* x_in    = (const float*)d_in[0];
    const float* v_first = (const float*)d_in[1];
    const float* k_first = (const float*)d_in[2];
    const float* state   = (const float*)d_in[3];
    const float* cosb    = (const float*)d_in[4];
    const float* sinb    = (const float*)d_in[5];
    const float* wavgk1  = (const float*)d_in[6];
    const float* w0      = (const float*)d_in[7];
    const float* w2      = (const float*)d_in[8];
    const float* a0      = (const float*)d_in[9];
    const float* a2      = (const float*)d_in[10];
    const float* v0      = (const float*)d_in[11];
    const float* v2      = (const float*)d_in[12];
    const float* g2      = (const float*)d_in[13];
    const float* k0      = (const float*)d_in[14];
    const float* k2      = (const float*)d_in[15];
    const float* r_k     = (const float*)d_in[16];
    const float* RKV     = (const float*)d_in[17];
    const float* O       = (const float*)d_in[18];
    const float* R_bias  = (const float*)d_in[19];
    const float* K_bias  = (const float*)d_in[20];
    const float* V_bias  = (const float*)d_in[21];
    const float* ln_r    = (const float*)d_in[22];
    const float* ln_k    = (const float*)d_in[23];
    const float* ln1     = (const float*)d_in[24];
    const float* ln2     = (const float*)d_in[25];

    if (ws_size < WS_NEED) return;  // need 213.4 MB (fits 256 MiB)

    char* ws = (char*)d_ws;
    u16*   BT1  = (u16*)(ws + OFF_BT1);
    u16*   W2T  = (u16*)(ws + OFF_W2T);
    u16*   OT   = (u16*)(ws + OFF_OT);
    u16*   XB   = (u16*)(ws + OFF_XB);
    float* Y1   = (float*)(ws + OFF_Y1);
    u16*   X2   = (u16*)(ws + OFF_X2);
    float* Y2   = (float*)(ws + OFF_Y2);
    float* RR   = (float*)(ws + OFF_RR);
    float* DEC  = (float*)(ws + OFF_DEC);
    float* KR   = (float*)(ws + OFF_KR);
    float* VV   = (float*)(ws + OFF_VV);
    float* AA   = (float*)(ws + OFF_AA);
    float* BB   = (float*)(ws + OFF_BB);
    float* OO   = (float*)(ws + OFF_OO);
    u16*   XG   = (u16*)(ws + OFF_XG);
    float* OUTR = (float*)(ws + OFF_OUTR);

    // P0: BT1 + XB (region C)
    k_prep_bt1<<<29696, 256, 0, stream>>>(wavgk1, RKV, BT1);
    k_rms1<<<2048, 256, 0, stream>>>(x_in, ln1, XB);
    // P1: GEMM1 -> Y1  (region A)
    k_gemm<<<dim3(16, 29), 256, 0, stream>>>(XB, BT1, Y1, 2048, N1, 2048);
    // P2: W2T + X2 overwrite BT1/XB (dead); GEMM2 -> Y2 (region B)
    k_prep_w2t<<<16128, 256, 0, stream>>>(w2, a2, g2, v2, k2, W2T);
    k_prep_x2<<<4608, 256, 0, stream>>>(Y1, X2);
    k_gemm<<<dim3(16, 56), 256, 0, stream>>>(X2, W2T, Y2, 2048, N2, K2W);
    // P3: recurrence operands (region D); Y1 dead after this
    k_prep_rec<<<2048, 256, 0, stream>>>(Y1, Y2, v_first, k_first, cosb, sinb,
                                         w0, a0, v0, k0, R_bias, K_bias, V_bias,
                                         ln_r, ln_k, RR, DEC, KR, VV, AA, BB);
    // P4: OT overwrites W2T/X2 (dead); recurrence -> OO (in old Y1 space)
    k_prep_ot<<<16384, 256, 0, stream>>>(O, OT);
    k_rec<<<64, 64, 0, stream>>>(RR, DEC, KR, VV, AA, BB, state, OO);
    // P5: gate -> XG (in old Y1 space); Y2 dead after this
    k_gate<<<2048, 256, 0, stream>>>(OO, RR, KR, VV, Y2, r_k, XG);
    // P6: GEMM3 -> OUTR (in old Y2 space); final norm
    k_gemm<<<dim3(16, 16), 256, 0, stream>>>(XG, OT, OUTR, 2048, 2048, 2048);
    k_final<<<2048, 256, 0, stream>>>(x_in, OUTR, ln2, (float*)d_out);
}

// Round 4
// 995.954 us; speedup vs baseline: 2.3840x; 2.3840x over previous
//
#include <hip/hip_runtime.h>

typedef unsigned short u16;
typedef unsigned int u32;

using f32x4 = __attribute__((ext_vector_type(4))) float;
using bf16x8 = __attribute__((ext_vector_type(8))) __bf16;

// ---------- constants ----------
#define HN 2048
#define KVD 512
#define TOKENS 2048          // B*T
#define N1 3712              // GEMM1 N (3648 padded to 29*128)
#define K2W 576              // GEMM2 K
#define N2 7168              // GEMM2 N: w(2048) a(2048) g(2048) v(512) k(512)

// ---------- workspace layout (bytes) — lifetime-aliased, peak 213.4 MB ----------
#define OFF_Y1   0ull
#define OFF_OO   0ull
#define OFF_XG   16777216ull
#define OFF_Y2   30408704ull
#define OFF_OUTR 30408704ull
#define OFF_BT1  89128960ull
#define OFF_XB   104333312ull
#define OFF_W2T  89128960ull
#define OFF_X2   97386496ull
#define OFF_OT   89128960ull
#define OFF_RR   112721920ull
#define OFF_DEC  129499136ull
#define OFF_KR   146276352ull
#define OFF_VV   163053568ull
#define OFF_AA   179830784ull
#define OFF_BB   196608000ull
#define WS_NEED  213385216ull

// ---------- helpers ----------
__device__ __forceinline__ u16 f2bf(float f) {
    u32 u = __float_as_uint(f);
    u32 r = u + 0x7fffu + ((u >> 16) & 1u);
    return (u16)(r >> 16);
}
__device__ __forceinline__ float sigm(float x) { return 1.f / (1.f + expf(-x)); }
__device__ __forceinline__ float wsum(float v) {
#pragma unroll
    for (int m = 32; m > 0; m >>= 1) v += __shfl_xor(v, m, 64);
    return v;
}
// broadcast lane l's value to all lanes (constant l -> v_readlane_b32 to SGPR)
__device__ __forceinline__ float rdlane(float v, int l) {
    return __uint_as_float(__builtin_amdgcn_readlane(__float_as_uint(v), l));
}

typedef __attribute__((address_space(1))) const void glob_t;
typedef __attribute__((address_space(3))) void lds_t;
__device__ __forceinline__ void gload_lds16(const void* g, void* l) {
    __builtin_amdgcn_global_load_lds((glob_t*)g, (lds_t*)l, 16, 0, 0);
}

// ---------- weight prep ----------
__global__ __launch_bounds__(256) void k_prep_bt1(const float* __restrict__ wavgk1,
                                                  const float* __restrict__ RKV,
                                                  u16* __restrict__ BT1) {
    int idx = blockIdx.x * 256 + threadIdx.x;   // n*2048 + k, n<3712
    int n = idx >> 11, k = idx & 2047;
    float v = 0.f;
    if (n < 576) v = wavgk1[(size_t)k * 576 + n];
    else if (n < 3648) v = RKV[(size_t)k * 3072 + (n - 576)];
    BT1[idx] = f2bf(v);
}

__global__ __launch_bounds__(256) void k_prep_w2t(const float* __restrict__ w2, const float* __restrict__ a2,
                                                  const float* __restrict__ g2, const float* __restrict__ v2,
                                                  const float* __restrict__ k2, u16* __restrict__ W2T) {
    int idx = blockIdx.x * 256 + threadIdx.x;   // n*576 + c, n<7168
    int n = idx / 576, c = idx - n * 576;
    float v = 0.f;
    if (n < 2048)      { if (c < 96)              v = w2[(size_t)c * 2048 + n]; }
    else if (n < 4096) { if (c >= 96 && c < 192)  v = a2[(size_t)(c - 96) * 2048 + (n - 2048)]; }
    else if (n < 6144) { if (c >= 192 && c < 448) v = g2[(size_t)(c - 192) * 2048 + (n - 4096)]; }
    else if (n < 6656) { if (c >= 448 && c < 512) v = v2[(size_t)(c - 448) * 512 + (n - 6144)]; }
    else               { if (c >= 512)            v = k2[(size_t)(c - 512) * 512 + (n - 6656)]; }
    W2T[idx] = f2bf(v);
}

__global__ __launch_bounds__(256) void k_prep_ot(const float* __restrict__ O, u16* __restrict__ OT) {
    int idx = blockIdx.x * 256 + threadIdx.x;   // n*2048 + k
    int n = idx >> 11, k = idx & 2047;
    OT[idx] = f2bf(O[(size_t)k * 2048 + n]);
}

// ---------- rmsnorm(x_in, ln1) -> bf16 ----------
__global__ __launch_bounds__(256) void k_rms1(const float* __restrict__ X,
                                              const float* __restrict__ ln1,
                                              u16* __restrict__ XB) {
    const int t = blockIdx.x, tid = threadIdx.x;
    const float* row = X + ((size_t)t << 11);
    float4 v0 = *(const float4*)(row + tid * 8);
    float4 v1 = *(const float4*)(row + tid * 8 + 4);
    float ss = v0.x*v0.x + v0.y*v0.y + v0.z*v0.z + v0.w*v0.w
             + v1.x*v1.x + v1.y*v1.y + v1.z*v1.z + v1.w*v1.w;
    ss = wsum(ss);
    __shared__ float red[4];
    if ((tid & 63) == 0) red[tid >> 6] = ss;
    __syncthreads();
    float scale = rsqrtf((red[0] + red[1] + red[2] + red[3]) * (1.f / 2048.f) + 1e-6f);
    float4 w0_ = *(const float4*)(ln1 + tid * 8);
    float4 w1_ = *(const float4*)(ln1 + tid * 8 + 4);
    u16* o = XB + ((size_t)t << 11) + tid * 8;
    o[0] = f2bf(v0.x * scale * w0_.x); o[1] = f2bf(v0.y * scale * w0_.y);
    o[2] = f2bf(v0.z * scale * w0_.z); o[3] = f2bf(v0.w * scale * w0_.w);
    o[4] = f2bf(v1.x * scale * w1_.x); o[5] = f2bf(v1.y * scale * w1_.y);
    o[6] = f2bf(v1.z * scale * w1_.z); o[7] = f2bf(v1.w * scale * w1_.w);
}

// ---------- generic bf16 MFMA GEMM: C(MxN f32) = A(MxK bf16) * Bt(NxK bf16)^T ----------
__global__ __launch_bounds__(256) void k_gemm(const u16* __restrict__ A,
                                              const u16* __restrict__ Bt,
                                              float* __restrict__ C,
                                              int M, int N, int K) {
    __shared__ __align__(16) u16 tA[4096];  // [128 rows][32 k]
    __shared__ __align__(16) u16 tB[4096];
    const int tid = threadIdx.x;
    const int w = tid >> 6, l = tid & 63;
    const int bm = blockIdx.x << 7, bn = blockIdx.y << 7;
    const int wm = (w >> 1) << 6, wn = (w & 1) << 6;
    const int lrow = l >> 2;        // 0..15
    const int lk = (l & 3) << 3;    // 0,8,16,24
    f32x4 acc[4][4] = {};
    const size_t rA0 = (size_t)(bm + (w << 4) + lrow) * K;
    const size_t rA1 = (size_t)(bm + ((w + 4) << 4) + lrow) * K;
    const size_t rB0 = (size_t)(bn + (w << 4) + lrow) * K;
    const size_t rB1 = (size_t)(bn + ((w + 4) << 4) + lrow) * K;
    const int frow = l & 15, koff = (l >> 4) << 3;
    for (int kt = 0; kt < K; kt += 32) {
        gload_lds16(A + rA0 + kt + lk, &tA[w << 9]);
        gload_lds16(A + rA1 + kt + lk, &tA[2048 + (w << 9)]);
        gload_lds16(Bt + rB0 + kt + lk, &tB[w << 9]);
        gload_lds16(Bt + rB1 + kt + lk, &tB[2048 + (w << 9)]);
        __syncthreads();
        bf16x8 av[4], bv[4];
#pragma unroll
        for (int i = 0; i < 4; ++i) {
            av[i] = *(const bf16x8*)&tA[((wm + (i << 4) + frow) << 5) + koff];
            bv[i] = *(const bf16x8*)&tB[((wn + (i << 4) + frow) << 5) + koff];
        }
#pragma unroll
        for (int i = 0; i < 4; ++i)
#pragma unroll
            for (int j = 0; j < 4; ++j)
                acc[i][j] = __builtin_amdgcn_mfma_f32_16x16x32_bf16(av[i], bv[j], acc[i][j], 0, 0, 0);
        __syncthreads();
    }
    const int crow = bm + wm + ((l >> 4) << 2);
    const int ccol = bn + wn + (l & 15);
#pragma unroll
    for (int i = 0; i < 4; ++i)
#pragma unroll
        for (int j = 0; j < 4; ++j)
#pragma unroll
            for (int jj = 0; jj < 4; ++jj)
                C[(size_t)(crow + (i << 4) + jj) * N + ccol + (j << 4)] = acc[i][j][jj];
}

// ---------- Y1 -> X2 (bf16): [tanh(xw) | xa | sigmoid(xg) | xv | xk] ----------
__global__ __launch_bounds__(256) void k_prep_x2(const float* __restrict__ Y1, u16* __restrict__ X2) {
    int idx = blockIdx.x * 256 + threadIdx.x;   // t*576 + c
    int t = idx / 576, c = idx - t * 576;
    const float* y1 = Y1 + (size_t)t * N1;
    float v;
    if (c < 96)       v = tanhf(y1[c]);
    else if (c < 192) v = y1[c];
    else if (c < 448) v = sigm(y1[c + 64]);
    else if (c < 512) v = y1[c - 256];
    else              v = y1[c];
    X2[idx] = f2bf(v);
}

// ---------- per-token recurrence prep ----------
__global__ __launch_bounds__(256) void k_prep_rec(
    const float* __restrict__ Y1, const float* __restrict__ Y2,
    const float* __restrict__ v_first, const float* __restrict__ k_first,
    const float* __restrict__ cosb, const float* __restrict__ sinb,
    const float* __restrict__ w0, const float* __restrict__ a0,
    const float* __restrict__ v0b, const float* __restrict__ k0b,
    const float* __restrict__ R_bias, const float* __restrict__ K_bias,
    const float* __restrict__ V_bias, const float* __restrict__ ln_r,
    const float* __restrict__ ln_k,
    float* __restrict__ RR, float* __restrict__ DEC, float* __restrict__ KR,
    float* __restrict__ VV, float* __restrict__ AA, float* __restrict__ BB) {
    const int t = blockIdx.x, tid = threadIdx.x;
    const int ww = tid >> 6, lane = tid & 63;
    const float* y1 = Y1 + (size_t)t * N1;
    const float* y2 = Y2 + (size_t)t * N2;
    const float cs = cosb[t * 64 + lane];
    const float sn = sinb[t * 64 + lane];
    const float sign = lane < 32 ? -1.f : 1.f;
    const size_t tb = (size_t)t << 11;
    __shared__ float kkv[512], vkv[512];
    // r: per-head rmsnorm + rope
#pragma unroll
    for (int i = 0; i < 8; ++i) {
        int h = ww * 8 + i, c = h * 64 + lane;
        float rr = y1[576 + c] + R_bias[c];
        float ssq = wsum(rr * rr);
        float rn = ln_r[lane] * rr * rsqrtf(ssq * (1.f / 64.f) + 1e-6f);
        float rot = sign * __shfl(rn, lane ^ 32, 64);
        RR[tb + c] = rn * cs + rot * sn;
    }
    // k,v kv-heads: rmsnorm+rope+mix
#pragma unroll
    for (int i = 0; i < 2; ++i) {
        int j = ww * 2 + i, c = j * 64 + lane;
        float kr = y1[2624 + c] + K_bias[c];
        float ssq = wsum(kr * kr);
        float kn = ln_k[lane] * kr * rsqrtf(ssq * (1.f / 64.f) + 1e-6f);
        float rot = sign * __shfl(kn, lane ^ 32, 64);
        float krope = kn * cs + rot * sn;
        float ksig = sigm(y2[6656 + c] + k0b[c]);
        kkv[c] = krope + (k_first[(size_t)t * 512 + c] - krope) * ksig;
        float vr = y1[3136 + c] + V_bias[c];
        float vsig = sigm(y2[6144 + c] + v0b[c]);
        vkv[c] = vr + (v_first[(size_t)t * 512 + c] - vr) * vsig;
    }
    __syncthreads();
    // per-head final recurrence operands
#pragma unroll
    for (int i = 0; i < 8; ++i) {
        int h = ww * 8 + i, c = h * 64 + lane;
        int ckv = (h >> 2) * 64 + lane;
        float kb = kkv[ckv], vb = vkv[ckv];
        float a_ = sigm(y2[2048 + c] + a0[c]);
        float wr = y2[c] + w0[c];
        float z = -wr;
        float sp = fmaxf(z, 0.f) + log1pf(expf(-fabsf(z)));
        float w_log = -sp - 0.5f;
        float ssq = wsum(kb * kb);
        float kk = kb / fmaxf(sqrtf(ssq), 1e-12f);
        DEC[tb + c] = expf(-expf(w_log));
        KR[tb + c] = kb * (1.f - w_log + a_);
        VV[tb + c] = vb;
        AA[tb + c] = -kk;
        BB[tb + c] = kk * a_;
    }
}

// ---------- sequential recurrence: 4 waves per (b,h); wave w owns S rows [16w,16w+16) ----------
// lane = v-column. Coefficients live in full-width VGPR loads; broadcast via
// v_readlane_b32 (constant lane index -> SGPR operand folded into v_fma_f32).
// Cross-wave coupling: sa and o k-reductions via LDS partials + 2 barriers/step.
__global__ __launch_bounds__(256) void k_rec4(
    const float* __restrict__ RRp, const float* __restrict__ DECp,
    const float* __restrict__ KRp, const float* __restrict__ VVp,
    const float* __restrict__ AAp, const float* __restrict__ BBp,
    const float* __restrict__ S0, float* __restrict__ OO) {
    const int bh = blockIdx.x;
    const int tid = threadIdx.x;
    const int w = tid >> 6, lane = tid & 63;
    float S[16];
    const float* s0 = S0 + ((size_t)bh << 12) + (w << 10);
#pragma unroll
    for (int j = 0; j < 16; ++j) S[j] = s0[(j << 6) + lane];
    __shared__ float sbuf[256];   // sa partials [w][lane]
    __shared__ float obuf[256];   // o partials  [w][lane]
    const size_t base = ((size_t)(bh >> 5) * 1024 * 2048) + ((size_t)(bh & 31) << 6) + lane;
    float cA = AAp[base], cD = DECp[base], cK = KRp[base],
          cB = BBp[base], cR = RRp[base], cV = VVp[base];
    for (int t = 0; t < 1024; ++t) {
        // sa partial over this wave's 16 k-rows
        float sp = 0.f;
#pragma unroll
        for (int j = 0; j < 16; ++j)
            sp = fmaf(rdlane(cA, (w << 4) + j), S[j], sp);
        sbuf[(w << 6) + lane] = sp;
        __syncthreads();
        const float sa = (sbuf[lane] + sbuf[64 + lane]) + (sbuf[128 + lane] + sbuf[192 + lane]);
        const float vt = cV;
        // state update + o partial
        float op = 0.f;
#pragma unroll
        for (int j = 0; j < 16; ++j) {
            const int kk = (w << 4) + j;
            float s = S[j] * rdlane(cD, kk);
            s = fmaf(rdlane(cK, kk), vt, s);
            s = fmaf(rdlane(cB, kk), sa, s);
            S[j] = s;
            op = fmaf(rdlane(cR, kk), s, op);
        }
        obuf[(w << 6) + lane] = op;
        // prefetch next step's coefficients (current ones fully consumed above)
        if (t < 1023) {
            const size_t nx = base + ((size_t)(t + 1) << 11);
            cA = AAp[nx]; cD = DECp[nx]; cK = KRp[nx];
            cB = BBp[nx]; cR = RRp[nx]; cV = VVp[nx];
        }
        __syncthreads();
        if (w == 0) {
            OO[base + ((size_t)t << 11)] =
                (obuf[lane] + obuf[64 + lane]) + (obuf[128 + lane] + obuf[192 + lane]);
        }
    }
}

// ---------- bonus + gate -> bf16 ----------
__global__ __launch_bounds__(256) void k_gate(
    const float* __restrict__ OOp, const float* __restrict__ RRp,
    const float* __restrict__ KRp, const float* __restrict__ VVp,
    const float* __restrict__ Y2, const float* __restrict__ r_k,
    u16* __restrict__ XG) {
    const int t = blockIdx.x, tid = threadIdx.x;
    const int ww = tid >> 6, lane = tid & 63;
    const size_t tb = (size_t)t << 11;
#pragma unroll
    for (int i = 0; i < 8; ++i) {
        int c = (ww * 8 + i) * 64 + lane;
        float pr = RRp[tb + c] * KRp[tb + c] * r_k[c];
        float dot = wsum(pr);
        float xx = OOp[tb + c] * 0.125f + dot * VVp[tb + c];
        float g = Y2[(size_t)t * N2 + 4096 + c];
        XG[tb + c] = f2bf(xx * g);
    }
}

// ---------- final residual + rmsnorm ----------
__global__ __launch_bounds__(256) void k_final(const float* __restrict__ x_in,
                                               const float* __restrict__ OUTR,
                                               const float* __restrict__ ln2,
                                               float* __restrict__ out) {
    const int t = blockIdx.x, tid = threadIdx.x;
    const float* xr = x_in + ((size_t)t << 11);
    const float* orow = OUTR + ((size_t)t << 11);
    float4 a0 = *(const float4*)(xr + tid * 8);
    float4 a1 = *(const float4*)(xr + tid * 8 + 4);
    float4 b0 = *(const float4*)(orow + tid * 8);
    float4 b1 = *(const float4*)(orow + tid * 8 + 4);
    float v[8] = {a0.x + b0.x, a0.y + b0.y, a0.z + b0.z, a0.w + b0.w,
                  a1.x + b1.x, a1.y + b1.y, a1.z + b1.z, a1.w + b1.w};
    float ss = 0.f;
#pragma unroll
    for (int i = 0; i < 8; ++i) ss = fmaf(v[i], v[i], ss);
    ss = wsum(ss);
    __shared__ float red[4];
    if ((tid & 63) == 0) red[tid >> 6] = ss;
    __syncthreads();
    float scale = rsqrtf((red[0] + red[1] + red[2] + red[3]) * (1.f / 2048.f) + 1e-6f);
    float* o = out + ((size_t)t << 11) + tid * 8;
#pragma unroll
    for (int i = 0; i < 8; ++i) o[i] = ln2[tid * 8 + i] * v[i] * scale;
}

extern "C" void kernel_launch(void* const* d_in, const int* in_sizes, int n_in,
                              void* d_out, int out_size, void* d_ws, size_t ws_size,
                              hipStream_t stream) {
    const float* x_in    = (const float*)d_in[0];
    const float* v_first = (const float*)d_in[1];
    const float* k_first = (const float*)d_in[2];
    const float* state   = (const float*)d_in[3];
    const float* cosb    = (const float*)d_in[4];
    const float* sinb    = (const float*)d_in[5];
    const float* wavgk1  = (const float*)d_in[6];
    const float* w0      = (const float*)d_in[7];
    const float* w2      = (const float*)d_in[8];
    const float* a0      = (const float*)d_in[9];
    const float* a2      = (const float*)d_in[10];
    const float* v0      = (const float*)d_in[11];
    const float* v2      = (const float*)d_in[12];
    const float* g2      = (const float*)d_in[13];
    const float* k0      = (const float*)d_in[14];
    const float* k2      = (const float*)d_in[15];
    const float* r_k     = (const float*)d_in[16];
    const float* RKV     = (const float*)d_in[17];
    const float* O       = (const float*)d_in[18];
    const float* R_bias  = (const float*)d_in[19];
    const float* K_bias  = (const float*)d_in[20];
    const float* V_bias  = (const float*)d_in[21];
    const float* ln_r    = (const float*)d_in[22];
    const float* ln_k    = (const float*)d_in[23];
    const float* ln1     = (const float*)d_in[24];
    const float* ln2     = (const float*)d_in[25];

    if (ws_size < WS_NEED) return;  // need 213.4 MB (fits 256 MiB)

    char* ws = (char*)d_ws;
    u16*   BT1  = (u16*)(ws + OFF_BT1);
    u16*   W2T  = (u16*)(ws + OFF_W2T);
    u16*   OT   = (u16*)(ws + OFF_OT);
    u16*   XB   = (u16*)(ws + OFF_XB);
    float* Y1   = (float*)(ws + OFF_Y1);
    u16*   X2   = (u16*)(ws + OFF_X2);
    float* Y2   = (float*)(ws + OFF_Y2);
    float* RR   = (float*)(ws + OFF_RR);
    float* DEC  = (float*)(ws + OFF_DEC);
    float* KR   = (float*)(ws + OFF_KR);
    float* VV   = (float*)(ws + OFF_VV);
    float* AA   = (float*)(ws + OFF_AA);
    float* BB   = (float*)(ws + OFF_BB);
    float* OO   = (float*)(ws + OFF_OO);
    u16*   XG   = (u16*)(ws + OFF_XG);
    float* OUTR = (float*)(ws + OFF_OUTR);

    // P0: BT1 + XB (region C)
    k_prep_bt1<<<29696, 256, 0, stream>>>(wavgk1, RKV, BT1);
    k_rms1<<<2048, 256, 0, stream>>>(x_in, ln1, XB);
    // P1: GEMM1 -> Y1  (region A)
    k_gemm<<<dim3(16, 29), 256, 0, stream>>>(XB, BT1, Y1, 2048, N1, 2048);
    // P2: W2T + X2 overwrite BT1/XB (dead); GEMM2 -> Y2 (region B)
    k_prep_w2t<<<16128, 256, 0, stream>>>(w2, a2, g2, v2, k2, W2T);
    k_prep_x2<<<4608, 256, 0, stream>>>(Y1, X2);
    k_gemm<<<dim3(16, 56), 256, 0, stream>>>(X2, W2T, Y2, 2048, N2, K2W);
    // P3: recurrence operands (region D); Y1 dead after this
    k_prep_rec<<<2048, 256, 0, stream>>>(Y1, Y2, v_first, k_first, cosb, sinb,
                                         w0, a0, v0, k0, R_bias, K_bias, V_bias,
                                         ln_r, ln_k, RR, DEC, KR, VV, AA, BB);
    // P4: OT overwrites W2T/X2 (dead); recurrence -> OO (in old Y1 space)
    k_prep_ot<<<16384, 256, 0, stream>>>(O, OT);
    k_rec4<<<64, 256, 0, stream>>>(RR, DEC, KR, VV, AA, BB, state, OO);
    // P5: gate -> XG (in old Y1 space); Y2 dead after this
    k_gate<<<2048, 256, 0, stream>>>(OO, RR, KR, VV, Y2, r_k, XG);
    // P6: GEMM3 -> OUTR (in old Y2 space); final norm
    k_gemm<<<dim3(16, 16), 256, 0, stream>>>(XG, OT, OUTR, 2048, 2048, 2048);
    k_final<<<2048, 256, 0, stream>>>(x_in, OUTR, ln2, (float*)d_out);
}

// Round 5
// 930.451 us; speedup vs baseline: 2.5518x; 1.0704x over previous
//
#include <hip/hip_runtime.h>

typedef unsigned short u16;
typedef unsigned int u32;

using f32x4 = __attribute__((ext_vector_type(4))) float;
using bf16x8 = __attribute__((ext_vector_type(8))) __bf16;

// ---------- constants ----------
#define HN 2048
#define KVD 512
#define TOKENS 2048          // B*T
#define N1 3712              // GEMM1 N (3648 padded to 29*128)
#define K2W 576              // GEMM2 K
#define N2 7168              // GEMM2 N: w(2048) a(2048) g(2048) v(512) k(512)

// ---------- workspace layout (bytes) — lifetime-aliased, peak 213.4 MB ----------
#define OFF_Y1   0ull
#define OFF_OO   0ull
#define OFF_XG   16777216ull
#define OFF_Y2   30408704ull
#define OFF_OUTR 30408704ull
#define OFF_BT1  89128960ull
#define OFF_XB   104333312ull
#define OFF_W2T  89128960ull
#define OFF_X2   97386496ull
#define OFF_OT   89128960ull
#define OFF_RR   112721920ull
#define OFF_DEC  129499136ull
#define OFF_KR   146276352ull
#define OFF_VV   163053568ull
#define OFF_AA   179830784ull
#define OFF_BB   196608000ull
#define WS_NEED  213385216ull

// ---------- helpers ----------
__device__ __forceinline__ u16 f2bf(float f) {
    u32 u = __float_as_uint(f);
    u32 r = u + 0x7fffu + ((u >> 16) & 1u);
    return (u16)(r >> 16);
}
__device__ __forceinline__ float sigm(float x) { return 1.f / (1.f + expf(-x)); }
__device__ __forceinline__ float wsum(float v) {
#pragma unroll
    for (int m = 32; m > 0; m >>= 1) v += __shfl_xor(v, m, 64);
    return v;
}
// broadcast lane l's value to all lanes (l wave-uniform -> v_readlane_b32 to SGPR)
__device__ __forceinline__ float rdlane(float v, int l) {
    return __uint_as_float(__builtin_amdgcn_readlane(__float_as_uint(v), l));
}

typedef __attribute__((address_space(1))) const void glob_t;
typedef __attribute__((address_space(3))) void lds_t;
__device__ __forceinline__ void gload_lds16(const void* g, void* l) {
    __builtin_amdgcn_global_load_lds((glob_t*)g, (lds_t*)l, 16, 0, 0);
}

// ---------- weight prep ----------
__global__ __launch_bounds__(256) void k_prep_bt1(const float* __restrict__ wavgk1,
                                                  const float* __restrict__ RKV,
                                                  u16* __restrict__ BT1) {
    int idx = blockIdx.x * 256 + threadIdx.x;   // n*2048 + k, n<3712
    int n = idx >> 11, k = idx & 2047;
    float v = 0.f;
    if (n < 576) v = wavgk1[(size_t)k * 576 + n];
    else if (n < 3648) v = RKV[(size_t)k * 3072 + (n - 576)];
    BT1[idx] = f2bf(v);
}

__global__ __launch_bounds__(256) void k_prep_w2t(const float* __restrict__ w2, const float* __restrict__ a2,
                                                  const float* __restrict__ g2, const float* __restrict__ v2,
                                                  const float* __restrict__ k2, u16* __restrict__ W2T) {
    int idx = blockIdx.x * 256 + threadIdx.x;   // n*576 + c, n<7168
    int n = idx / 576, c = idx - n * 576;
    float v = 0.f;
    if (n < 2048)      { if (c < 96)              v = w2[(size_t)c * 2048 + n]; }
    else if (n < 4096) { if (c >= 96 && c < 192)  v = a2[(size_t)(c - 96) * 2048 + (n - 2048)]; }
    else if (n < 6144) { if (c >= 192 && c < 448) v = g2[(size_t)(c - 192) * 2048 + (n - 4096)]; }
    else if (n < 6656) { if (c >= 448 && c < 512) v = v2[(size_t)(c - 448) * 512 + (n - 6144)]; }
    else               { if (c >= 512)            v = k2[(size_t)(c - 512) * 512 + (n - 6656)]; }
    W2T[idx] = f2bf(v);
}

__global__ __launch_bounds__(256) void k_prep_ot(const float* __restrict__ O, u16* __restrict__ OT) {
    int idx = blockIdx.x * 256 + threadIdx.x;   // n*2048 + k
    int n = idx >> 11, k = idx & 2047;
    OT[idx] = f2bf(O[(size_t)k * 2048 + n]);
}

// ---------- rmsnorm(x_in, ln1) -> bf16 ----------
__global__ __launch_bounds__(256) void k_rms1(const float* __restrict__ X,
                                              const float* __restrict__ ln1,
                                              u16* __restrict__ XB) {
    const int t = blockIdx.x, tid = threadIdx.x;
    const float* row = X + ((size_t)t << 11);
    float4 v0 = *(const float4*)(row + tid * 8);
    float4 v1 = *(const float4*)(row + tid * 8 + 4);
    float ss = v0.x*v0.x + v0.y*v0.y + v0.z*v0.z + v0.w*v0.w
             + v1.x*v1.x + v1.y*v1.y + v1.z*v1.z + v1.w*v1.w;
    ss = wsum(ss);
    __shared__ float red[4];
    if ((tid & 63) == 0) red[tid >> 6] = ss;
    __syncthreads();
    float scale = rsqrtf((red[0] + red[1] + red[2] + red[3]) * (1.f / 2048.f) + 1e-6f);
    float4 w0_ = *(const float4*)(ln1 + tid * 8);
    float4 w1_ = *(const float4*)(ln1 + tid * 8 + 4);
    u16* o = XB + ((size_t)t << 11) + tid * 8;
    o[0] = f2bf(v0.x * scale * w0_.x); o[1] = f2bf(v0.y * scale * w0_.y);
    o[2] = f2bf(v0.z * scale * w0_.z); o[3] = f2bf(v0.w * scale * w0_.w);
    o[4] = f2bf(v1.x * scale * w1_.x); o[5] = f2bf(v1.y * scale * w1_.y);
    o[6] = f2bf(v1.z * scale * w1_.z); o[7] = f2bf(v1.w * scale * w1_.w);
}

// ---------- generic bf16 MFMA GEMM: C(MxN f32) = A(MxK bf16) * Bt(NxK bf16)^T ----------
__global__ __launch_bounds__(256) void k_gemm(const u16* __restrict__ A,
                                              const u16* __restrict__ Bt,
                                              float* __restrict__ C,
                                              int M, int N, int K) {
    __shared__ __align__(16) u16 tA[4096];  // [128 rows][32 k]
    __shared__ __align__(16) u16 tB[4096];
    const int tid = threadIdx.x;
    const int w = tid >> 6, l = tid & 63;
    const int bm = blockIdx.x << 7, bn = blockIdx.y << 7;
    const int wm = (w >> 1) << 6, wn = (w & 1) << 6;
    const int lrow = l >> 2;        // 0..15
    const int lk = (l & 3) << 3;    // 0,8,16,24
    f32x4 acc[4][4] = {};
    const size_t rA0 = (size_t)(bm + (w << 4) + lrow) * K;
    const size_t rA1 = (size_t)(bm + ((w + 4) << 4) + lrow) * K;
    const size_t rB0 = (size_t)(bn + (w << 4) + lrow) * K;
    const size_t rB1 = (size_t)(bn + ((w + 4) << 4) + lrow) * K;
    const int frow = l & 15, koff = (l >> 4) << 3;
    for (int kt = 0; kt < K; kt += 32) {
        gload_lds16(A + rA0 + kt + lk, &tA[w << 9]);
        gload_lds16(A + rA1 + kt + lk, &tA[2048 + (w << 9)]);
        gload_lds16(Bt + rB0 + kt + lk, &tB[w << 9]);
        gload_lds16(Bt + rB1 + kt + lk, &tB[2048 + (w << 9)]);
        __syncthreads();
        bf16x8 av[4], bv[4];
#pragma unroll
        for (int i = 0; i < 4; ++i) {
            av[i] = *(const bf16x8*)&tA[((wm + (i << 4) + frow) << 5) + koff];
            bv[i] = *(const bf16x8*)&tB[((wn + (i << 4) + frow) << 5) + koff];
        }
#pragma unroll
        for (int i = 0; i < 4; ++i)
#pragma unroll
            for (int j = 0; j < 4; ++j)
                acc[i][j] = __builtin_amdgcn_mfma_f32_16x16x32_bf16(av[i], bv[j], acc[i][j], 0, 0, 0);
        __syncthreads();
    }
    const int crow = bm + wm + ((l >> 4) << 2);
    const int ccol = bn + wn + (l & 15);
#pragma unroll
    for (int i = 0; i < 4; ++i)
#pragma unroll
        for (int j = 0; j < 4; ++j)
#pragma unroll
            for (int jj = 0; jj < 4; ++jj)
                C[(size_t)(crow + (i << 4) + jj) * N + ccol + (j << 4)] = acc[i][j][jj];
}

// ---------- Y1 -> X2 (bf16): [tanh(xw) | xa | sigmoid(xg) | xv | xk] ----------
__global__ __launch_bounds__(256) void k_prep_x2(const float* __restrict__ Y1, u16* __restrict__ X2) {
    int idx = blockIdx.x * 256 + threadIdx.x;   // t*576 + c
    int t = idx / 576, c = idx - t * 576;
    const float* y1 = Y1 + (size_t)t * N1;
    float v;
    if (c < 96)       v = tanhf(y1[c]);
    else if (c < 192) v = y1[c];
    else if (c < 448) v = sigm(y1[c + 64]);
    else if (c < 512) v = y1[c - 256];
    else              v = y1[c];
    X2[idx] = f2bf(v);
}

// ---------- per-token recurrence prep ----------
__global__ __launch_bounds__(256) void k_prep_rec(
    const float* __restrict__ Y1, const float* __restrict__ Y2,
    const float* __restrict__ v_first, const float* __restrict__ k_first,
    const float* __restrict__ cosb, const float* __restrict__ sinb,
    const float* __restrict__ w0, const float* __restrict__ a0,
    const float* __restrict__ v0b, const float* __restrict__ k0b,
    const float* __restrict__ R_bias, const float* __restrict__ K_bias,
    const float* __restrict__ V_bias, const float* __restrict__ ln_r,
    const float* __restrict__ ln_k,
    float* __restrict__ RR, float* __restrict__ DEC, float* __restrict__ KR,
    float* __restrict__ VV, float* __restrict__ AA, float* __restrict__ BB) {
    const int t = blockIdx.x, tid = threadIdx.x;
    const int ww = tid >> 6, lane = tid & 63;
    const float* y1 = Y1 + (size_t)t * N1;
    const float* y2 = Y2 + (size_t)t * N2;
    const float cs = cosb[t * 64 + lane];
    const float sn = sinb[t * 64 + lane];
    const float sign = lane < 32 ? -1.f : 1.f;
    const size_t tb = (size_t)t << 11;
    __shared__ float kkv[512], vkv[512];
    // r: per-head rmsnorm + rope
#pragma unroll
    for (int i = 0; i < 8; ++i) {
        int h = ww * 8 + i, c = h * 64 + lane;
        float rr = y1[576 + c] + R_bias[c];
        float ssq = wsum(rr * rr);
        float rn = ln_r[lane] * rr * rsqrtf(ssq * (1.f / 64.f) + 1e-6f);
        float rot = sign * __shfl(rn, lane ^ 32, 64);
        RR[tb + c] = rn * cs + rot * sn;
    }
    // k,v kv-heads: rmsnorm+rope+mix
#pragma unroll
    for (int i = 0; i < 2; ++i) {
        int j = ww * 2 + i, c = j * 64 + lane;
        float kr = y1[2624 + c] + K_bias[c];
        float ssq = wsum(kr * kr);
        float kn = ln_k[lane] * kr * rsqrtf(ssq * (1.f / 64.f) + 1e-6f);
        float rot = sign * __shfl(kn, lane ^ 32, 64);
        float krope = kn * cs + rot * sn;
        float ksig = sigm(y2[6656 + c] + k0b[c]);
        kkv[c] = krope + (k_first[(size_t)t * 512 + c] - krope) * ksig;
        float vr = y1[3136 + c] + V_bias[c];
        float vsig = sigm(y2[6144 + c] + v0b[c]);
        vkv[c] = vr + (v_first[(size_t)t * 512 + c] - vr) * vsig;
    }
    __syncthreads();
    // per-head final recurrence operands
#pragma unroll
    for (int i = 0; i < 8; ++i) {
        int h = ww * 8 + i, c = h * 64 + lane;
        int ckv = (h >> 2) * 64 + lane;
        float kb = kkv[ckv], vb = vkv[ckv];
        float a_ = sigm(y2[2048 + c] + a0[c]);
        float wr = y2[c] + w0[c];
        float z = -wr;
        float sp = fmaxf(z, 0.f) + log1pf(expf(-fabsf(z)));
        float w_log = -sp - 0.5f;
        float ssq = wsum(kb * kb);
        float kk = kb / fmaxf(sqrtf(ssq), 1e-12f);
        DEC[tb + c] = expf(-expf(w_log));
        KR[tb + c] = kb * (1.f - w_log + a_);
        VV[tb + c] = vb;
        AA[tb + c] = -kk;
        BB[tb + c] = kk * a_;
    }
}

// ---------- sequential recurrence: 8 waves per (b,h); wave w owns S rows [8w,8w+8) ----------
// lane = v-column. One barrier per step: sa partials of step t and o partials of
// step t-1 become visible at the same barrier (ping-pong LDS buffers by t&1).
// Coefficients broadcast via v_readlane (wave-uniform idx); distance-2 prefetch
// via 2x-unrolled loop with two register sets.
__global__ __launch_bounds__(512) void k_rec8(
    const float* __restrict__ RRp, const float* __restrict__ DECp,
    const float* __restrict__ KRp, const float* __restrict__ VVp,
    const float* __restrict__ AAp, const float* __restrict__ BBp,
    const float* __restrict__ S0, float* __restrict__ OO) {
    const int bh = blockIdx.x;
    const int tid = threadIdx.x;
    const int wu = __builtin_amdgcn_readfirstlane(tid >> 6);  // wave id 0..7 (SGPR)
    const int lane = tid & 63;
    float S[8];
    const float* s0 = S0 + ((size_t)bh << 12) + (wu << 9);
#pragma unroll
    for (int j = 0; j < 8; ++j) S[j] = s0[(j << 6) + lane];
    __shared__ float sbuf[2][512];
    __shared__ float obuf[2][512];
    const size_t base = ((size_t)(bh >> 5) * 1024 * 2048) + ((size_t)(bh & 31) << 6) + lane;
    // coefficient sets: set0 = even steps, set1 = odd steps
    float cA0 = AAp[base],        cD0 = DECp[base],        cK0 = KRp[base],
          cB0 = BBp[base],        cR0 = RRp[base],         cV0 = VVp[base];
    float cA1 = AAp[base + 2048], cD1 = DECp[base + 2048], cK1 = KRp[base + 2048],
          cB1 = BBp[base + 2048], cR1 = RRp[base + 2048],  cV1 = VVp[base + 2048];

#define REC_STEP(T, P, cA, cD, cK, cB, cR, cV)                                   \
    {                                                                            \
        float sp = 0.f;                                                          \
        _Pragma("unroll") for (int j = 0; j < 8; ++j)                            \
            sp = fmaf(rdlane(cA, (wu << 3) + j), S[j], sp);                      \
        sbuf[P][(wu << 6) + lane] = sp;                                          \
        __syncthreads();                                                         \
        float sa = 0.f;                                                          \
        _Pragma("unroll") for (int q = 0; q < 8; ++q)                            \
            sa += sbuf[P][(q << 6) + lane];                                      \
        if ((T) > 0 && wu == ((T) & 7)) {                                        \
            float o = 0.f;                                                       \
            _Pragma("unroll") for (int q = 0; q < 8; ++q)                        \
                o += obuf[(P) ^ 1][(q << 6) + lane];                             \
            OO[base + ((size_t)((T) - 1) << 11)] = o;                            \
        }                                                                        \
        float op = 0.f;                                                          \
        _Pragma("unroll") for (int j = 0; j < 8; ++j) {                          \
            const int kk = (wu << 3) + j;                                        \
            float s = S[j] * rdlane(cD, kk);                                     \
            s = fmaf(rdlane(cK, kk), cV, s);                                     \
            s = fmaf(rdlane(cB, kk), sa, s);                                     \
            S[j] = s;                                                            \
            op = fmaf(rdlane(cR, kk), s, op);                                    \
        }                                                                        \
        obuf[P][(wu << 6) + lane] = op;                                          \
        if ((T) + 2 < 1024) {                                                    \
            const size_t nx = base + ((size_t)((T) + 2) << 11);                  \
            cA = AAp[nx]; cD = DECp[nx]; cK = KRp[nx];                           \
            cB = BBp[nx]; cR = RRp[nx]; cV = VVp[nx];                            \
        }                                                                        \
    }

    for (int t2 = 0; t2 < 512; ++t2) {
        const int t0 = t2 * 2;
        REC_STEP(t0,     0, cA0, cD0, cK0, cB0, cR0, cV0);
        REC_STEP(t0 + 1, 1, cA1, cD1, cK1, cB1, cR1, cV1);
    }
    __syncthreads();
    if (wu == 0) {
        float o = 0.f;
#pragma unroll
        for (int q = 0; q < 8; ++q) o += obuf[1][(q << 6) + lane];
        OO[base + ((size_t)1023 << 11)] = o;
    }
#undef REC_STEP
}

// ---------- bonus + gate -> bf16 ----------
__global__ __launch_bounds__(256) void k_gate(
    const float* __restrict__ OOp, const float* __restrict__ RRp,
    const float* __restrict__ KRp, const float* __restrict__ VVp,
    const float* __restrict__ Y2, const float* __restrict__ r_k,
    u16* __restrict__ XG) {
    const int t = blockIdx.x, tid = threadIdx.x;
    const int ww = tid >> 6, lane = tid & 63;
    const size_t tb = (size_t)t << 11;
#pragma unroll
    for (int i = 0; i < 8; ++i) {
        int c = (ww * 8 + i) * 64 + lane;
        float pr = RRp[tb + c] * KRp[tb + c] * r_k[c];
        float dot = wsum(pr);
        float xx = OOp[tb + c] * 0.125f + dot * VVp[tb + c];
        float g = Y2[(size_t)t * N2 + 4096 + c];
        XG[tb + c] = f2bf(xx * g);
    }
}

// ---------- final residual + rmsnorm ----------
__global__ __launch_bounds__(256) void k_final(const float* __restrict__ x_in,
                                               const float* __restrict__ OUTR,
                                               const float* __restrict__ ln2,
                                               float* __restrict__ out) {
    const int t = blockIdx.x, tid = threadIdx.x;
    const float* xr = x_in + ((size_t)t << 11);
    const float* orow = OUTR + ((size_t)t << 11);
    float4 a0 = *(const float4*)(xr + tid * 8);
    float4 a1 = *(const float4*)(xr + tid * 8 + 4);
    float4 b0 = *(const float4*)(orow + tid * 8);
    float4 b1 = *(const float4*)(orow + tid * 8 + 4);
    float v[8] = {a0.x + b0.x, a0.y + b0.y, a0.z + b0.z, a0.w + b0.w,
                  a1.x + b1.x, a1.y + b1.y, a1.z + b1.z, a1.w + b1.w};
    float ss = 0.f;
#pragma unroll
    for (int i = 0; i < 8; ++i) ss = fmaf(v[i], v[i], ss);
    ss = wsum(ss);
    __shared__ float red[4];
    if ((tid & 63) == 0) red[tid >> 6] = ss;
    __syncthreads();
    float scale = rsqrtf((red[0] + red[1] + red[2] + red[3]) * (1.f / 2048.f) + 1e-6f);
    float* o = out + ((size_t)t << 11) + tid * 8;
#pragma unroll
    for (int i = 0; i < 8; ++i) o[i] = ln2[tid * 8 + i] * v[i] * scale;
}

extern "C" void kernel_launch(void* const* d_in, const int* in_sizes, int n_in,
                              void* d_out, int out_size, void* d_ws, size_t ws_size,
                              hipStream_t stream) {
    const float* x_in    = (const float*)d_in[0];
    const float* v_first = (const float*)d_in[1];
    const float* k_first = (const float*)d_in[2];
    const float* state   = (const float*)d_in[3];
    const float* cosb    = (const float*)d_in[4];
    const float* sinb    = (const float*)d_in[5];
    const float* wavgk1  = (const float*)d_in[6];
    const float* w0      = (const float*)d_in[7];
    const float* w2      = (const float*)d_in[8];
    const float* a0      = (const float*)d_in[9];
    const float* a2      = (const float*)d_in[10];
    const float* v0      = (const float*)d_in[11];
    const float* v2      = (const float*)d_in[12];
    const float* g2      = (const float*)d_in[13];
    const float* k0      = (const float*)d_in[14];
    const float* k2      = (const float*)d_in[15];
    const float* r_k     = (const float*)d_in[16];
    const float* RKV     = (const float*)d_in[17];
    const float* O       = (const float*)d_in[18];
    const float* R_bias  = (const float*)d_in[19];
    const float* K_bias  = (const float*)d_in[20];
    const float* V_bias  = (const float*)d_in[21];
    const float* ln_r    = (const float*)d_in[22];
    const float* ln_k    = (const float*)d_in[23];
    const float* ln1     = (const float*)d_in[24];
    const float* ln2     = (const float*)d_in[25];

    if (ws_size < WS_NEED) return;  // need 213.4 MB (fits 256 MiB)

    char* ws = (char*)d_ws;
    u16*   BT1  = (u16*)(ws + OFF_BT1);
    u16*   W2T  = (u16*)(ws + OFF_W2T);
    u16*   OT   = (u16*)(ws + OFF_OT);
    u16*   XB   = (u16*)(ws + OFF_XB);
    float* Y1   = (float*)(ws + OFF_Y1);
    u16*   X2   = (u16*)(ws + OFF_X2);
    float* Y2   = (float*)(ws + OFF_Y2);
    float* RR   = (float*)(ws + OFF_RR);
    float* DEC  = (float*)(ws + OFF_DEC);
    float* KR   = (float*)(ws + OFF_KR);
    float* VV   = (float*)(ws + OFF_VV);
    float* AA   = (float*)(ws + OFF_AA);
    float* BB   = (float*)(ws + OFF_BB);
    float* OO   = (float*)(ws + OFF_OO);
    u16*   XG   = (u16*)(ws + OFF_XG);
    float* OUTR = (float*)(ws + OFF_OUTR);

    // P0: BT1 + XB (region C)
    k_prep_bt1<<<29696, 256, 0, stream>>>(wavgk1, RKV, BT1);
    k_rms1<<<2048, 256, 0, stream>>>(x_in, ln1, XB);
    // P1: GEMM1 -> Y1  (region A)
    k_gemm<<<dim3(16, 29), 256, 0, stream>>>(XB, BT1, Y1, 2048, N1, 2048);
    // P2: W2T + X2 overwrite BT1/XB (dead); GEMM2 -> Y2 (region B)
    k_prep_w2t<<<16128, 256, 0, stream>>>(w2, a2, g2, v2, k2, W2T);
    k_prep_x2<<<4608, 256, 0, stream>>>(Y1, X2);
    k_gemm<<<dim3(16, 56), 256, 0, stream>>>(X2, W2T, Y2, 2048, N2, K2W);
    // P3: recurrence operands (region D); Y1 dead after this
    k_prep_rec<<<2048, 256, 0, stream>>>(Y1, Y2, v_first, k_first, cosb, sinb,
                                         w0, a0, v0, k0, R_bias, K_bias, V_bias,
                                         ln_r, ln_k, RR, DEC, KR, VV, AA, BB);
    // P4: OT overwrites W2T/X2 (dead); recurrence -> OO (in old Y1 space)
    k_prep_ot<<<16384, 256, 0, stream>>>(O, OT);
    k_rec8<<<64, 512, 0, stream>>>(RR, DEC, KR, VV, AA, BB, state, OO);
    // P5: gate -> XG (in old Y1 space); Y2 dead after this
    k_gate<<<2048, 256, 0, stream>>>(OO, RR, KR, VV, Y2, r_k, XG);
    // P6: GEMM3 -> OUTR (in old Y2 space); final norm
    k_gemm<<<dim3(16, 16), 256, 0, stream>>>(XG, OT, OUTR, 2048, 2048, 2048);
    k_final<<<2048, 256, 0, stream>>>(x_in, OUTR, ln2, (float*)d_out);
}